// Round 13
// baseline (699.398 us; speedup 1.0000x reference)
//
#include <hip/hip_runtime.h>

// GCN 3-layer forward on gfx950.
// Round 13: XCD-local column-sliced gather for 128-wide layers.
//  - grid = 8 slices x row-blocks; slice = blockIdx&7 (round-robin -> XCD).
//    Per-XCD working set of Thi = 3.2MB < 4MB L2 -> edge reads become L2 hits
//    (were L3 misses at ~2.4 TB/s; R9/R12 showed transaction/byte bound).
//  - pairs compacted to 4B: row<<15 | bf16(norm) (read 8x now).
//  - self-loop folded in as an edge (norm=dinv^2); rows padded to 8;
//    pads written by scan3 (26MB memset removed).
//  - layer-3 (64-wide) gather keeps R12 row-wave form, new pair format.
// GEMM unchanged (R11: single Ah*Bh pass, LDS B, LDS epilogue).

#define IN_CH 128

typedef __attribute__((ext_vector_type(8))) short bf16x8;
typedef __attribute__((ext_vector_type(4))) float f32x4;

__device__ inline unsigned short f2bf_rne(float f) {
    unsigned u = __float_as_uint(f);
    unsigned r = (u + 0x7FFFu + ((u >> 16) & 1u)) >> 16;
    return (unsigned short)r;
}
__device__ inline float bf2f(unsigned short h) {
    return __uint_as_float(((unsigned)h) << 16);
}
__device__ inline float bf2f_lo(unsigned m) {
    return __uint_as_float(m << 16);
}
__device__ inline float bf2f_hi(unsigned m) {
    return __uint_as_float(m & 0xffff0000u);
}

// ---------------- degree count ----------------
__global__ __launch_bounds__(256) void cnt_k(const int* __restrict__ dst,
                                             int* __restrict__ cnt, int E) {
    int e = blockIdx.x * 256 + threadIdx.x;
    if (e < E) atomicAdd(&cnt[dst[e]], 1);
}

// ---------------- scan stage 1 on PADDED counts (+ dinv from real) --------
// padded count = (cnt+1 self + pad to 8) = (cnt+8) & ~7
__global__ __launch_bounds__(256) void scan1_k(const int* __restrict__ cnt,
                                               int* __restrict__ bsum,
                                               float* __restrict__ dinv, int N) {
    __shared__ int s[256];
    int tid = threadIdx.x;
    int i = blockIdx.x * 256 + tid;
    int vr = (i < N) ? cnt[i] : 0;
    if (i < N) dinv[i] = rsqrtf((float)vr + 1.0f);
    s[tid] = (i < N) ? ((vr + 8) & ~7) : 0;
    __syncthreads();
    for (int off = 128; off > 0; off >>= 1) {
        if (tid < off) s[tid] += s[tid + off];
        __syncthreads();
    }
    if (tid == 0) bsum[blockIdx.x] = s[0];
}

__global__ __launch_bounds__(512) void scan2_k(int* __restrict__ bsum, int nb) {
    __shared__ int s[512];
    __shared__ int carry_s;
    int tid = threadIdx.x;
    if (tid == 0) carry_s = 0;
    __syncthreads();
    for (int base = 0; base < nb; base += 512) {
        int c = carry_s;
        int i = base + tid;
        int v = (i < nb) ? bsum[i] : 0;
        s[tid] = v;
        __syncthreads();
        for (int off = 1; off < 512; off <<= 1) {
            int t = (tid >= off) ? s[tid - off] : 0;
            __syncthreads();
            s[tid] += t;
            __syncthreads();
        }
        if (i < nb) bsum[i] = s[tid] - v + c;
        __syncthreads();
        if (tid == 0) carry_s = c + s[511];
        __syncthreads();
    }
}

// scan3: rowstart[N+1]; writes self edge + zero pads; cur = start+1
__global__ __launch_bounds__(256) void scan3_k(const int* __restrict__ cnt,
                                               const int* __restrict__ bsum,
                                               const float* __restrict__ dinv,
                                               int* __restrict__ rowstart,
                                               int* __restrict__ cur,
                                               unsigned* __restrict__ cpairs, int N) {
    __shared__ int s[256];
    int tid = threadIdx.x;
    int i = blockIdx.x * 256 + tid;
    int cr = (i < N) ? cnt[i] : 0;
    int v = (i < N) ? ((cr + 8) & ~7) : 0;
    s[tid] = v;
    __syncthreads();
    for (int off = 1; off < 256; off <<= 1) {
        int t = (tid >= off) ? s[tid - off] : 0;
        __syncthreads();
        s[tid] += t;
        __syncthreads();
    }
    if (i < N) {
        int st = s[tid] - v + bsum[blockIdx.x];
        rowstart[i] = st;
        if (i == N - 1) rowstart[N] = st + v;
        float dn = dinv[i];
        cpairs[st] = ((unsigned)i << 15) | (f2bf_rne(dn * dn) & 0x7FFFu);  // self
        cur[i] = st + 1;
        for (int k = st + 1 + cr; k < st + v; ++k) cpairs[k] = 0u;  // pads
    }
}

// ---------------- fill (compact 4B pairs) + W conversion ------------------
__device__ inline void convw_one(const float* W, unsigned short* hi, int FOUT, int id) {
    int n = id >> 7, k = id & 127;
    hi[id] = f2bf_rne(W[k * FOUT + n]);
}

__global__ __launch_bounds__(256) void fill_conv_k(
    const int* __restrict__ src, const int* __restrict__ dst,
    const float* __restrict__ dinv, int* __restrict__ cur,
    unsigned* __restrict__ cpairs, int E, int fillBlocks,
    const float* __restrict__ W1, const float* __restrict__ W2,
    const float* __restrict__ W3,
    unsigned short* __restrict__ W1h, unsigned short* __restrict__ W2h,
    unsigned short* __restrict__ W3h) {
    if ((int)blockIdx.x < fillBlocks) {
        int e = blockIdx.x * 256 + threadIdx.x;
        if (e < E) {
            int s = src[e], d = dst[e];
            float nrm = dinv[s] * dinv[d];
            int pos = atomicAdd(&cur[d], 1);
            cpairs[pos] = ((unsigned)s << 15) | (f2bf_rne(nrm) & 0x7FFFu);
        }
    } else {
        int id = (blockIdx.x - fillBlocks) * 256 + threadIdx.x;
        if (id < 16384) convw_one(W1, W1h, 128, id);
        else if (id < 32768) convw_one(W2, W2h, 128, id - 16384);
        else if (id < 40960) convw_one(W3, W3h, 64, id - 32768);
    }
}

// ---------------- MFMA GEMM: T[N][FOUT] = A[N][128] @ W[128][FOUT] ----------
// C = Ah*Bh, fp32 acc, output bf16 hi only. Block = 4 waves x 16 rows.
// Bh staged in LDS (R8); LDS-staged coalesced epilogue (R10).
__device__ inline bf16x8 cvt8(const float* __restrict__ p) {
    float4 v0 = *(const float4*)p;
    float4 v1 = *(const float4*)(p + 4);
    bf16x8 h;
    h[0] = (short)f2bf_rne(v0.x); h[1] = (short)f2bf_rne(v0.y);
    h[2] = (short)f2bf_rne(v0.z); h[3] = (short)f2bf_rne(v0.w);
    h[4] = (short)f2bf_rne(v1.x); h[5] = (short)f2bf_rne(v1.y);
    h[6] = (short)f2bf_rne(v1.z); h[7] = (short)f2bf_rne(v1.w);
    return h;
}

template <int FOUT, bool AF32>
__global__ __launch_bounds__(256) void mfma_gemm(const float* __restrict__ Af,
                                                 const unsigned short* __restrict__ Ahi,
                                                 const unsigned short* __restrict__ Bhi,
                                                 unsigned short* __restrict__ Thi,
                                                 int N) {
    constexpr int NCT = FOUT / 16;
    constexpr int BSTRIDE = 136;
    constexpr int CSTRIDE = FOUT + 8;
    constexpr int BU = FOUT * BSTRIDE;
    constexpr int CU = 64 * CSTRIDE;
    constexpr int SMEMU = (BU > CU) ? BU : CU;
    __shared__ unsigned short smem[SMEMU];

    const int tid = threadIdx.x;
    const int wv = tid >> 6, lane = tid & 63;
    const int quad = lane >> 4, l16 = lane & 15;
    const int row0 = blockIdx.x * 64 + wv * 16;

#pragma unroll
    for (int it = 0; it < FOUT / 16; ++it) {
        int i = it * 256 + tid;
        int r = i >> 4, c = (i & 15) * 8;
        *(bf16x8*)(&smem[r * BSTRIDE + c]) = *(const bf16x8*)(Bhi + (size_t)r * 128 + c);
    }
    __syncthreads();

    f32x4 acc[NCT];
#pragma unroll
    for (int ct = 0; ct < NCT; ++ct)
        acc[ct] = (f32x4){0.f, 0.f, 0.f, 0.f};

    const int ra = AF32 ? min(row0 + l16, N - 1) : (row0 + l16);

#pragma unroll
    for (int ks = 0; ks < 4; ++ks) {
        const int ko = ks * 32 + quad * 8;
        bf16x8 ah;
        if (AF32) {
            ah = cvt8(Af + (size_t)ra * 128 + ko);
        } else {
            ah = *(const bf16x8*)(Ahi + (size_t)ra * 128 + ko);
        }
#pragma unroll
        for (int ct = 0; ct < NCT; ++ct) {
            bf16x8 bh = *(const bf16x8*)(&smem[(ct * 16 + l16) * BSTRIDE + ko]);
            acc[ct] = __builtin_amdgcn_mfma_f32_16x16x32_bf16(ah, bh, acc[ct], 0, 0, 0);
        }
    }

    __syncthreads();
    const int lrow = wv * 16 + quad * 4;
#pragma unroll
    for (int ct = 0; ct < NCT; ++ct) {
        const int col = ct * 16 + l16;
#pragma unroll
        for (int r = 0; r < 4; ++r)
            smem[(lrow + r) * CSTRIDE + col] = f2bf_rne(acc[ct][r]);
    }
    __syncthreads();
    constexpr int CH = FOUT / 8;
#pragma unroll
    for (int i = 0; i < 64 * CH / 256; ++i) {
        int ci = i * 256 + tid;
        int r = ci / CH, c = (ci % CH) * 8;
        int grow = blockIdx.x * 64 + r;
        if (grow < N)
            *(uint4*)(Thi + (size_t)grow * FOUT + c) = *(const uint4*)&smem[r * CSTRIDE + c];
    }
}

// ---------------- sliced gather (FOUT=128): 8 col-slices, XCD-local -------
// blockIdx&7 = slice (16 cols); 64 lanes = 8 edges x 8 dwords; self+bias
// folded; rows padded to 8 (pads read row 0, norm 0).
template <bool SPLIT>
__global__ __launch_bounds__(256) void gatherS_k(const int* __restrict__ rowstart,
                                                 const unsigned* __restrict__ cpairs,
                                                 const unsigned short* __restrict__ Thi,
                                                 const float* __restrict__ bias,
                                                 float* __restrict__ out,
                                                 unsigned short* __restrict__ outHi,
                                                 int N) {
    const int wave = threadIdx.x >> 6;
    const int lane = threadIdx.x & 63;
    const int s = blockIdx.x & 7;
    const int row = (blockIdx.x >> 3) * 4 + wave;
    if (row >= N) return;
    const int e = lane >> 3, d = lane & 7;
    const int start = rowstart[row], end = rowstart[row + 1];
    const char* tbase = (const char*)Thi;
    const int colB = s * 32 + d * 4;

    float ax = 0.f, ay = 0.f;
    for (int j = start; j < end; j += 8) {
        unsigned p = cpairs[j + e];
        float n = bf2f((unsigned short)(p & 0x7FFFu));
        unsigned m = *(const unsigned*)(tbase + ((size_t)(p >> 15) << 8) + colB);
        ax += n * bf2f_lo(m);
        ay += n * bf2f_hi(m);
    }
    ax += __shfl_xor(ax, 8); ax += __shfl_xor(ax, 16); ax += __shfl_xor(ax, 32);
    ay += __shfl_xor(ay, 8); ay += __shfl_xor(ay, 16); ay += __shfl_xor(ay, 32);

    if (e == 0) {
        float2 bb = *(const float2*)(bias + s * 16 + d * 2);
        ax += bb.x;
        ay += bb.y;
        if (SPLIT) {
            float vx = fmaxf(ax, 0.f), vy = fmaxf(ay, 0.f);
            unsigned hw = (unsigned)f2bf_rne(vx) | ((unsigned)f2bf_rne(vy) << 16);
            *(unsigned*)((char*)outHi + (size_t)row * 256 + colB) = hw;
        } else {
            float2 o; o.x = ax; o.y = ay;
            *(float2*)(out + (size_t)row * 128 + s * 16 + d * 2) = o;
        }
    }
}

// ---------------- layer-3 gather (FOUT=64): R12 row-wave form -------------
__global__ __launch_bounds__(256) void gather64_k(const int* __restrict__ rowstart,
                                                  const unsigned* __restrict__ cpairs,
                                                  const unsigned short* __restrict__ Thi,
                                                  const float* __restrict__ bias,
                                                  float* __restrict__ out, int N) {
    const int wave = threadIdx.x >> 6;
    const int lane = threadIdx.x & 63;
    const int row = blockIdx.x * 4 + wave;
    if (row >= N) return;
    const int start = rowstart[row], end = rowstart[row + 1];
    const char* tbase = (const char*)Thi;
    const int laneB = lane * 2;
    float acc = bias[lane];

    for (int j = start; j < end; j += 8) {
        uint4 pa = *(const uint4*)(cpairs + j);
        uint4 pb = *(const uint4*)(cpairs + j + 4);
        unsigned pp[8] = {pa.x, pa.y, pa.z, pa.w, pb.x, pb.y, pb.z, pb.w};
        float mv[8], nv[8];
#pragma unroll
        for (int k = 0; k < 8; ++k) {
            nv[k] = bf2f((unsigned short)(pp[k] & 0x7FFFu));
            mv[k] = bf2f(*(const unsigned short*)(tbase + ((size_t)(pp[k] >> 15) << 7) + laneB));
        }
#pragma unroll
        for (int k = 0; k < 8; ++k) acc += nv[k] * mv[k];
    }
    out[(size_t)row * 64 + lane] = acc;
}

extern "C" void kernel_launch(void* const* d_in, const int* in_sizes, int n_in,
                              void* d_out, int out_size, void* d_ws, size_t ws_size,
                              hipStream_t stream) {
    const float* x  = (const float*)d_in[0];
    const int* eidx = (const int*)d_in[1];
    const float* W1 = (const float*)d_in[2];
    const float* b1 = (const float*)d_in[3];
    const float* W2 = (const float*)d_in[4];
    const float* b2 = (const float*)d_in[5];
    const float* W3 = (const float*)d_in[6];
    const float* b3 = (const float*)d_in[7];
    float* out = (float*)d_out;

    const int N = in_sizes[0] / IN_CH;
    const int E = in_sizes[1] / 2;
    const int* src = eidx;
    const int* dst = eidx + E;
    const int Npad = ((N + 127) / 128) * 128;
    const int nb = (N + 255) / 256;
    const size_t Emax = (size_t)E + 8 * (size_t)N;  // padded-pairs upper bound

    auto align = [](size_t v) { return (v + 255) / 256 * 256; };
    char* p = (char*)d_ws;
    int* cnt = (int*)p;            p += align((size_t)N * 4);
    int* rowstart = (int*)p;       p += align((size_t)(N + 1) * 4);
    int* cur = (int*)p;            p += align((size_t)N * 4);
    int* bsum = (int*)p;           p += align((size_t)nb * 4);
    float* dinv = (float*)p;       p += align((size_t)N * 4);
    unsigned* cpairs = (unsigned*)p;  p += align(Emax * 4);
    unsigned short* Ahi = (unsigned short*)p;  p += align((size_t)Npad * 128 * 2);
    unsigned short* Thi = (unsigned short*)p;  p += align((size_t)Npad * 128 * 2);
    unsigned short* W1h = (unsigned short*)p;  p += align(128 * 128 * 2);
    unsigned short* W2h = (unsigned short*)p;  p += align(128 * 128 * 2);
    unsigned short* W3h = (unsigned short*)p;

    // ---- CSR build (once; reused by all 3 layers) ----
    hipMemsetAsync(cnt, 0, (size_t)N * 4, stream);
    cnt_k<<<(E + 255) / 256, 256, 0, stream>>>(dst, cnt, E);
    scan1_k<<<nb, 256, 0, stream>>>(cnt, bsum, dinv, N);
    scan2_k<<<1, 512, 0, stream>>>(bsum, nb);
    scan3_k<<<nb, 256, 0, stream>>>(cnt, bsum, dinv, rowstart, cur, cpairs, N);
    const int fillBlocks = (E + 255) / 256;
    fill_conv_k<<<fillBlocks + 160, 256, 0, stream>>>(src, dst, dinv, cur, cpairs,
                                                      E, fillBlocks, W1, W2, W3,
                                                      W1h, W2h, W3h);

    const int gemm_blocks = (N + 63) / 64;
    const int gS_blocks = ((N + 3) / 4) * 8;  // 8 slices
    const int g64_blocks = (N + 3) / 4;

    // Layer 1 (A = x fp32, converted in-register)
    mfma_gemm<128, true><<<gemm_blocks, 256, 0, stream>>>(x, nullptr, W1h, Thi, N);
    gatherS_k<true><<<gS_blocks, 256, 0, stream>>>(rowstart, cpairs, Thi, b1,
                                                   nullptr, Ahi, N);
    // Layer 2
    mfma_gemm<128, false><<<gemm_blocks, 256, 0, stream>>>(nullptr, Ahi, W2h, Thi, N);
    gatherS_k<true><<<gS_blocks, 256, 0, stream>>>(rowstart, cpairs, Thi, b2,
                                                   nullptr, Ahi, N);
    // Layer 3
    mfma_gemm<64, false><<<gemm_blocks, 256, 0, stream>>>(nullptr, Ahi, W3h, Thi, N);
    gather64_k<<<g64_blocks, 256, 0, stream>>>(rowstart, cpairs, Thi, b3, out, N);
}